// Round 1
// baseline (8460.143 us; speedup 1.0000x reference)
//
#include <hip/hip_runtime.h>
#include <hip/hip_bf16.h>
#include <math.h>

// Problem constants
#define D_MODEL 1024
#define N_LAYERS 4
#define D_STATE 16
#define D_CONV 4
#define D_INNER 2048
#define DT_RANK 65
#define B_SZ 2
#define SEQ_L 2048
#define EPS_LN 1e-5f

#define NROWS (B_SZ * SEQ_L)          // 4096 token rows
#define DBC_N (DT_RANK + 2 * D_STATE) // 97

// ---------------------------------------------------------------------------
// Generic NT GEMM: C[m,n] = sum_k A[m*lda+k] * B[n*ldb+k]  (+ Cres[m*N+n])
// 64x64 tile, BK=16, 256 threads, 4x4 per thread. fp32.
// ---------------------------------------------------------------------------
#define BM 64
#define BN 64
#define BK 16
__global__ __launch_bounds__(256) void gemm_nt(
    const float* __restrict__ A, const float* __restrict__ B,
    float* __restrict__ C, const float* __restrict__ Cres,
    int M, int N, int K, int lda, int ldb)
{
    __shared__ float As[BK][BM + 1];
    __shared__ float Bs[BK][BN + 1];

    const int m0 = blockIdx.y * BM;
    const int n0 = blockIdx.x * BN;
    const int tid = threadIdx.x;
    const int tx = tid & 15;   // n group
    const int ty = tid >> 4;   // m group

    float acc[4][4] = {};

    for (int k0 = 0; k0 < K; k0 += BK) {
        // load A tile (BM x BK) and B tile (BN x BK), 4 rows per thread
        const int c = tid & 15;          // k within tile
        const int rbase = tid >> 4;      // 0..15
        #pragma unroll
        for (int i = 0; i < 4; i++) {
            const int r = rbase + i * 16;       // 0..63
            const int gk = k0 + c;
            const int gm = m0 + r;
            const int gn = n0 + r;
            As[c][r] = (gm < M && gk < K) ? A[(size_t)gm * lda + gk] : 0.f;
            Bs[c][r] = (gn < N && gk < K) ? B[(size_t)gn * ldb + gk] : 0.f;
        }
        __syncthreads();

        #pragma unroll
        for (int k = 0; k < BK; k++) {
            float a[4], b[4];
            #pragma unroll
            for (int i = 0; i < 4; i++) a[i] = As[k][ty * 4 + i];
            #pragma unroll
            for (int j = 0; j < 4; j++) b[j] = Bs[k][tx * 4 + j];
            #pragma unroll
            for (int i = 0; i < 4; i++)
                #pragma unroll
                for (int j = 0; j < 4; j++)
                    acc[i][j] = fmaf(a[i], b[j], acc[i][j]);
        }
        __syncthreads();
    }

    #pragma unroll
    for (int i = 0; i < 4; i++) {
        const int gm = m0 + ty * 4 + i;
        if (gm >= M) continue;
        #pragma unroll
        for (int j = 0; j < 4; j++) {
            const int gn = n0 + tx * 4 + j;
            if (gn < N) {
                float v = acc[i][j];
                if (Cres) v += Cres[(size_t)gm * N + gn];
                C[(size_t)gm * N + gn] = v;
            }
        }
    }
}

// ---------------------------------------------------------------------------
// Depthwise causal conv (D_CONV=4) + bias + SiLU.
// xr is the low half (d<2048) of xz rows (stride 2*D_INNER).
// ---------------------------------------------------------------------------
__global__ __launch_bounds__(256) void conv_silu_kernel(
    const float* __restrict__ xz, const float* __restrict__ conv_w,
    const float* __restrict__ conv_b, float* __restrict__ xc)
{
    const size_t idx = (size_t)blockIdx.x * 256 + threadIdx.x;
    if (idx >= (size_t)NROWS * D_INNER) return;
    const int d = (int)(idx & (D_INNER - 1));
    const size_t bt = idx >> 11;              // b*L + t
    const int t = (int)(bt & (SEQ_L - 1));

    float acc = conv_b[d];
    #pragma unroll
    for (int j = 0; j < D_CONV; j++) {
        const int tt = t + j - (D_CONV - 1);
        if (tt >= 0) {
            const long row = (long)bt + j - (D_CONV - 1);
            acc = fmaf(xz[(size_t)row * (2 * D_INNER) + d], conv_w[d * D_CONV + j], acc);
        }
    }
    const float s = acc / (1.f + __expf(-acc));
    xc[idx] = s;
}

// ---------------------------------------------------------------------------
// dt = softplus(lin + b_dt[d])
// ---------------------------------------------------------------------------
__global__ __launch_bounds__(256) void softplus_bias_kernel(
    const float* __restrict__ lin, const float* __restrict__ b_dt,
    float* __restrict__ dt)
{
    const size_t idx = (size_t)blockIdx.x * 256 + threadIdx.x;
    if (idx >= (size_t)NROWS * D_INNER) return;
    const int d = (int)(idx & (D_INNER - 1));
    const float v = lin[idx] + b_dt[d];
    dt[idx] = fmaxf(v, 0.f) + log1pf(__expf(-fabsf(v)));
}

// ---------------------------------------------------------------------------
// Selective scan. Block = 256 threads = 16 d-channels x 16 states.
// grid = (D_INNER/16, B). Sequential over L with 32-step LDS chunks.
// Output fused: y = (scan_y + D_skip*u) * silu(z)
// ---------------------------------------------------------------------------
#define SCH 32
__global__ __launch_bounds__(256) void scan_kernel(
    const float* __restrict__ dt,    // (NROWS, D_INNER)
    const float* __restrict__ dbc,   // (NROWS, 97)
    const float* __restrict__ xc,    // u (NROWS, D_INNER)
    const float* __restrict__ xz,    // z at col offset D_INNER, stride 2*D_INNER
    const float* __restrict__ A_log, // (D_INNER, 16)
    const float* __restrict__ D_skip,
    float* __restrict__ y)           // (NROWS, D_INNER)
{
    const int b = blockIdx.y;
    const int d0 = blockIdx.x * 16;
    const int tid = threadIdx.x;
    const int dl = tid >> 4;   // 0..15 channel-in-block
    const int n = tid & 15;    // state index
    const int d = d0 + dl;

    const float Adn = -__expf(A_log[d * D_STATE + n]);
    const float Dd = D_skip[d];

    __shared__ float dt_s[SCH][16], u_s[SCH][16], z_s[SCH][16];
    __shared__ float B_s[SCH][16], C_s[SCH][16];

    float h = 0.f;
    for (int t0 = 0; t0 < SEQ_L; t0 += SCH) {
        #pragma unroll
        for (int i = 0; i < 2; i++) {
            const int idx = tid + i * 256;    // 0..511
            const int tt = idx >> 4;
            const int col = idx & 15;
            const size_t row = (size_t)(b * SEQ_L + t0 + tt);
            dt_s[tt][col] = dt[row * D_INNER + d0 + col];
            u_s[tt][col]  = xc[row * D_INNER + d0 + col];
            z_s[tt][col]  = xz[row * (2 * D_INNER) + D_INNER + d0 + col];
            B_s[tt][col]  = dbc[row * DBC_N + DT_RANK + col];
            C_s[tt][col]  = dbc[row * DBC_N + DT_RANK + D_STATE + col];
        }
        __syncthreads();

        for (int tt = 0; tt < SCH; tt++) {
            const float dtv = dt_s[tt][dl];
            const float uv = u_s[tt][dl];
            const float a = __expf(dtv * Adn);
            h = fmaf(a, h, dtv * uv * B_s[tt][n]);
            float yp = h * C_s[tt][n];
            yp += __shfl_xor(yp, 1);
            yp += __shfl_xor(yp, 2);
            yp += __shfl_xor(yp, 4);
            yp += __shfl_xor(yp, 8);
            if (n == 0) {
                const float zv = z_s[tt][dl];
                const float sig = 1.f / (1.f + __expf(-zv));
                y[(size_t)(b * SEQ_L + t0 + tt) * D_INNER + d] =
                    (yp + Dd * uv) * (zv * sig);
            }
        }
        __syncthreads();
    }
}

// ---------------------------------------------------------------------------
// Final LayerNorm over D_MODEL=1024. One block (256 thr) per token row.
// ---------------------------------------------------------------------------
__global__ __launch_bounds__(256) void layernorm_kernel(
    const float* __restrict__ x, const float* __restrict__ w,
    const float* __restrict__ bb, float* __restrict__ out)
{
    __shared__ float red[8];
    const int row = blockIdx.x;
    const float* xr = x + (size_t)row * D_MODEL;
    const int tid = threadIdx.x;

    float v[4];
    float s = 0.f;
    #pragma unroll
    for (int i = 0; i < 4; i++) { v[i] = xr[tid + i * 256]; s += v[i]; }
    #pragma unroll
    for (int off = 32; off >= 1; off >>= 1) s += __shfl_xor(s, off);
    const int wid = tid >> 6;
    if ((tid & 63) == 0) red[wid] = s;
    __syncthreads();
    const float mu = (red[0] + red[1] + red[2] + red[3]) * (1.f / D_MODEL);

    float vs = 0.f;
    #pragma unroll
    for (int i = 0; i < 4; i++) { const float dd = v[i] - mu; vs = fmaf(dd, dd, vs); }
    #pragma unroll
    for (int off = 32; off >= 1; off >>= 1) vs += __shfl_xor(vs, off);
    if ((tid & 63) == 0) red[4 + wid] = vs;
    __syncthreads();
    const float var = (red[4] + red[5] + red[6] + red[7]) * (1.f / D_MODEL);
    const float inv = rsqrtf(var + EPS_LN);

    #pragma unroll
    for (int i = 0; i < 4; i++) {
        const int c = tid + i * 256;
        out[(size_t)row * D_MODEL + c] = (v[i] - mu) * inv * w[c] + bb[c];
    }
}

// ---------------------------------------------------------------------------
extern "C" void kernel_launch(void* const* d_in, const int* in_sizes, int n_in,
                              void* d_out, int out_size, void* d_ws, size_t ws_size,
                              hipStream_t stream)
{
    const float* x_in   = (const float*)d_in[0];
    const float* W_in   = (const float*)d_in[1];
    const float* conv_w = (const float*)d_in[2];
    const float* conv_b = (const float*)d_in[3];
    const float* W_x    = (const float*)d_in[4];
    const float* W_dt   = (const float*)d_in[5];
    const float* b_dt   = (const float*)d_in[6];
    const float* A_log  = (const float*)d_in[7];
    const float* D_skip = (const float*)d_in[8];
    const float* W_out  = (const float*)d_in[9];
    const float* ln_w   = (const float*)d_in[10];
    const float* ln_b   = (const float*)d_in[11];
    float* out = (float*)d_out;

    float* buf_x   = (float*)d_ws;                              // NROWS*1024
    float* buf_xz  = buf_x  + (size_t)NROWS * D_MODEL;          // NROWS*4096
    float* buf_xc  = buf_xz + (size_t)NROWS * 2 * D_INNER;      // NROWS*2048
    float* buf_dbc = buf_xc + (size_t)NROWS * D_INNER;          // NROWS*97
    float* buf_dt  = buf_dbc + (size_t)NROWS * DBC_N;           // NROWS*2048
    float* buf_y   = buf_dt + (size_t)NROWS * D_INNER;          // NROWS*2048

    hipMemcpyAsync(buf_x, x_in, (size_t)NROWS * D_MODEL * sizeof(float),
                   hipMemcpyDeviceToDevice, stream);

    const dim3 blk(256);
    const int n_el = NROWS * D_INNER;

    for (int layer = 0; layer < N_LAYERS; layer++) {
        // xz = x @ W_in^T   (M=4096, N=4096, K=1024)
        gemm_nt<<<dim3(2 * D_INNER / BN, NROWS / BM), blk, 0, stream>>>(
            buf_x, W_in, buf_xz, nullptr, NROWS, 2 * D_INNER, D_MODEL, D_MODEL, D_MODEL);
        // conv + silu -> xc
        conv_silu_kernel<<<(n_el + 255) / 256, blk, 0, stream>>>(
            buf_xz, conv_w, conv_b, buf_xc);
        // dbc = xc @ W_x^T  (M=4096, N=97, K=2048)
        gemm_nt<<<dim3((DBC_N + BN - 1) / BN, NROWS / BM), blk, 0, stream>>>(
            buf_xc, W_x, buf_dbc, nullptr, NROWS, DBC_N, D_INNER, D_INNER, D_INNER);
        // dt_lin = dt_low @ W_dt^T  (M=4096, N=2048, K=65; A has lda=97)
        gemm_nt<<<dim3(D_INNER / BN, NROWS / BM), blk, 0, stream>>>(
            buf_dbc, W_dt, buf_dt, nullptr, NROWS, D_INNER, DT_RANK, DBC_N, DT_RANK);
        // dt = softplus(dt_lin + b_dt)
        softplus_bias_kernel<<<(n_el + 255) / 256, blk, 0, stream>>>(
            buf_dt, b_dt, buf_dt);
        // selective scan + gating -> y
        scan_kernel<<<dim3(D_INNER / 16, B_SZ), blk, 0, stream>>>(
            buf_dt, buf_dbc, buf_xc, buf_xz, A_log, D_skip, buf_y);
        // x = y @ W_out^T + x   (M=4096, N=1024, K=2048), in-place residual
        gemm_nt<<<dim3(D_MODEL / BN, NROWS / BM), blk, 0, stream>>>(
            buf_y, W_out, buf_x, buf_x, NROWS, D_MODEL, D_INNER, D_INNER, D_INNER);
    }

    layernorm_kernel<<<NROWS, blk, 0, stream>>>(buf_x, ln_w, ln_b, out);
}

// Round 2
// 4110.733 us; speedup vs baseline: 2.0581x; 2.0581x over previous
//
#include <hip/hip_runtime.h>
#include <hip/hip_bf16.h>
#include <math.h>

// Problem constants
#define D_MODEL 1024
#define N_LAYERS 4
#define D_STATE 16
#define D_CONV 4
#define D_INNER 2048
#define DT_RANK 65
#define B_SZ 2
#define SEQ_L 2048
#define EPS_LN 1e-5f

#define NROWS (B_SZ * SEQ_L)          // 4096 token rows
#define DBC_N (DT_RANK + 2 * D_STATE) // 97

typedef __bf16 bf16x8 __attribute__((ext_vector_type(8)));
typedef float floatx4 __attribute__((ext_vector_type(4)));

// ---------------------------------------------------------------------------
// async global->LDS 16B per lane. LDS dest is wave-uniform base + lane*16.
// ---------------------------------------------------------------------------
__device__ __forceinline__ void async_copy16(const void* gsrc, void* lds_dst)
{
    __builtin_amdgcn_global_load_lds(
        (const __attribute__((address_space(1))) void*)gsrc,
        (__attribute__((address_space(3))) void*)lds_dst,
        16, 0, 0);
}

// ---------------------------------------------------------------------------
// MFMA bf16 GEMM (NT): C[m,n] = sum_k A[m*K+k]*B[n*K+k]  (A:MxK, B:NxK bf16)
// 128x128 tile, BK=32, 256 threads = 4 waves (2x2 of 64x64), 16x16x32 MFMA.
// FUSE: C = acc + Cres (fp32) and also writes bf16 copy to Cbf.
// Requires M%128==0, N%128==0, K%32==0.
// ---------------------------------------------------------------------------
template <bool FUSE>
__global__ __launch_bounds__(256) void gemm_mfma_nt(
    const __bf16* __restrict__ A, const __bf16* __restrict__ B,
    float* __restrict__ C, const float* __restrict__ Cres,
    __bf16* __restrict__ Cbf, int M, int N, int K)
{
    __shared__ __bf16 As[128 * 32];
    __shared__ __bf16 Bs[128 * 32];

    const int tid = threadIdx.x;
    const int lane = tid & 63;
    const int w = tid >> 6;          // wave 0..3
    const int wm = w & 1;            // wave row (m) 0..1
    const int wn = w >> 1;           // wave col (n) 0..1
    const int m0 = blockIdx.y * 128;
    const int n0 = blockIdx.x * 128;

    const int lrow = lane >> 2;          // 0..15 row within 16-row group
    const int lcol8 = (lane & 3) * 8;    // k element offset for staging
    const int fr = lane & 15;            // fragment row/col
    const int fk = (lane >> 4) * 8;      // fragment k offset

    floatx4 acc[4][4];
    #pragma unroll
    for (int i = 0; i < 4; i++)
        #pragma unroll
        for (int j = 0; j < 4; j++)
            acc[i][j] = floatx4{0.f, 0.f, 0.f, 0.f};

    for (int k0 = 0; k0 < K; k0 += 32) {
        // stage A and B tiles: wave w loads 16-row groups {2w, 2w+1} of each
        #pragma unroll
        for (int g2 = 0; g2 < 2; g2++) {
            const int g = w * 2 + g2;
            const __bf16* ga = A + (size_t)(m0 + g * 16 + lrow) * K + k0 + lcol8;
            async_copy16(ga, &As[g * 512]);
            const __bf16* gb = B + (size_t)(n0 + g * 16 + lrow) * K + k0 + lcol8;
            async_copy16(gb, &Bs[g * 512]);
        }
        __syncthreads();   // compiler drains vmcnt before barrier

        bf16x8 af[4], bf[4];
        #pragma unroll
        for (int i = 0; i < 4; i++)
            af[i] = *(const bf16x8*)&As[(wm * 64 + i * 16 + fr) * 32 + fk];
        #pragma unroll
        for (int j = 0; j < 4; j++)
            bf[j] = *(const bf16x8*)&Bs[(wn * 64 + j * 16 + fr) * 32 + fk];

        #pragma unroll
        for (int i = 0; i < 4; i++)
            #pragma unroll
            for (int j = 0; j < 4; j++)
                acc[i][j] = __builtin_amdgcn_mfma_f32_16x16x32_bf16(
                    af[i], bf[j], acc[i][j], 0, 0, 0);

        __syncthreads();   // protect LDS before next staging
    }

    // epilogue: C/D layout col=lane&15, row=(lane>>4)*4+reg
    const int crow = (lane >> 4) * 4;
    const int ccol = lane & 15;
    #pragma unroll
    for (int i = 0; i < 4; i++) {
        #pragma unroll
        for (int j = 0; j < 4; j++) {
            #pragma unroll
            for (int r = 0; r < 4; r++) {
                const int gm = m0 + wm * 64 + i * 16 + crow + r;
                const int gn = n0 + wn * 64 + j * 16 + ccol;
                float v = acc[i][j][r];
                if (FUSE) {
                    v += Cres[(size_t)gm * N + gn];
                    Cbf[(size_t)gm * N + gn] = (__bf16)v;
                }
                C[(size_t)gm * N + gn] = v;
            }
        }
    }
}

// ---------------------------------------------------------------------------
// fp32 NT GEMM for the small matmuls (N=97 / K=65). 64x64 tile, BK=16.
// ---------------------------------------------------------------------------
#define BM 64
#define BN 64
#define BK 16
__global__ __launch_bounds__(256) void gemm_nt(
    const float* __restrict__ A, const float* __restrict__ B,
    float* __restrict__ C, const float* __restrict__ Cres,
    int M, int N, int K, int lda, int ldb)
{
    __shared__ float As[BK][BM + 4];   // +4 pad: tile stores 2-way (free)
    __shared__ float Bs[BK][BN + 4];

    const int m0 = blockIdx.y * BM;
    const int n0 = blockIdx.x * BN;
    const int tid = threadIdx.x;
    const int tx = tid & 15;
    const int ty = tid >> 4;

    float acc[4][4] = {};

    for (int k0 = 0; k0 < K; k0 += BK) {
        const int c = tid & 15;
        const int rbase = tid >> 4;
        #pragma unroll
        for (int i = 0; i < 4; i++) {
            const int r = rbase + i * 16;
            const int gk = k0 + c;
            const int gm = m0 + r;
            const int gn = n0 + r;
            As[c][r] = (gm < M && gk < K) ? A[(size_t)gm * lda + gk] : 0.f;
            Bs[c][r] = (gn < N && gk < K) ? B[(size_t)gn * ldb + gk] : 0.f;
        }
        __syncthreads();

        #pragma unroll
        for (int k = 0; k < BK; k++) {
            float a[4], b[4];
            #pragma unroll
            for (int i = 0; i < 4; i++) a[i] = As[k][ty * 4 + i];
            #pragma unroll
            for (int j = 0; j < 4; j++) b[j] = Bs[k][tx * 4 + j];
            #pragma unroll
            for (int i = 0; i < 4; i++)
                #pragma unroll
                for (int j = 0; j < 4; j++)
                    acc[i][j] = fmaf(a[i], b[j], acc[i][j]);
        }
        __syncthreads();
    }

    #pragma unroll
    for (int i = 0; i < 4; i++) {
        const int gm = m0 + ty * 4 + i;
        if (gm >= M) continue;
        #pragma unroll
        for (int j = 0; j < 4; j++) {
            const int gn = n0 + tx * 4 + j;
            if (gn < N) {
                float v = acc[i][j];
                if (Cres) v += Cres[(size_t)gm * N + gn];
                C[(size_t)gm * N + gn] = v;
            }
        }
    }
}

// ---------------------------------------------------------------------------
// fp32 -> bf16 cast, 4 elems/thread (n % 1024 == 0 for all uses)
// ---------------------------------------------------------------------------
__global__ __launch_bounds__(256) void cast_bf16_kernel(
    const float* __restrict__ in, __bf16* __restrict__ out, int n)
{
    const int i = (blockIdx.x * 256 + threadIdx.x) * 4;
    if (i >= n) return;
    const float4 v = *(const float4*)(in + i);
    out[i + 0] = (__bf16)v.x;
    out[i + 1] = (__bf16)v.y;
    out[i + 2] = (__bf16)v.z;
    out[i + 3] = (__bf16)v.w;
}

// ---------------------------------------------------------------------------
// Depthwise causal conv (D_CONV=4) + bias + SiLU.
// ---------------------------------------------------------------------------
__global__ __launch_bounds__(256) void conv_silu_kernel(
    const float* __restrict__ xz, const float* __restrict__ conv_w,
    const float* __restrict__ conv_b, float* __restrict__ xc)
{
    const size_t idx = (size_t)blockIdx.x * 256 + threadIdx.x;
    if (idx >= (size_t)NROWS * D_INNER) return;
    const int d = (int)(idx & (D_INNER - 1));
    const size_t bt = idx >> 11;
    const int t = (int)(bt & (SEQ_L - 1));

    float acc = conv_b[d];
    #pragma unroll
    for (int j = 0; j < D_CONV; j++) {
        const int tt = t + j - (D_CONV - 1);
        if (tt >= 0) {
            const long row = (long)bt + j - (D_CONV - 1);
            acc = fmaf(xz[(size_t)row * (2 * D_INNER) + d], conv_w[d * D_CONV + j], acc);
        }
    }
    xc[idx] = acc / (1.f + __expf(-acc));
}

// ---------------------------------------------------------------------------
// dt = softplus(lin + b_dt[d])
// ---------------------------------------------------------------------------
__global__ __launch_bounds__(256) void softplus_bias_kernel(
    const float* __restrict__ lin, const float* __restrict__ b_dt,
    float* __restrict__ dt)
{
    const size_t idx = (size_t)blockIdx.x * 256 + threadIdx.x;
    if (idx >= (size_t)NROWS * D_INNER) return;
    const int d = (int)(idx & (D_INNER - 1));
    const float v = lin[idx] + b_dt[d];
    dt[idx] = fmaxf(v, 0.f) + log1pf(__expf(-fabsf(v)));
}

// ---------------------------------------------------------------------------
// Selective scan. 256 thr = 16 d x 16 states; grid (D_INNER/16, B).
// Writes y as bf16 (only consumer is the bf16 GEMM4).
// ---------------------------------------------------------------------------
#define SCH 32
__global__ __launch_bounds__(256) void scan_kernel(
    const float* __restrict__ dt, const float* __restrict__ dbc,
    const float* __restrict__ xc, const float* __restrict__ xz,
    const float* __restrict__ A_log, const float* __restrict__ D_skip,
    __bf16* __restrict__ y)
{
    const int b = blockIdx.y;
    const int d0 = blockIdx.x * 16;
    const int tid = threadIdx.x;
    const int dl = tid >> 4;
    const int n = tid & 15;
    const int d = d0 + dl;

    const float Adn = -__expf(A_log[d * D_STATE + n]);
    const float Dd = D_skip[d];

    __shared__ float dt_s[SCH][16], u_s[SCH][16], z_s[SCH][16];
    __shared__ float B_s[SCH][16], C_s[SCH][16];

    float h = 0.f;
    for (int t0 = 0; t0 < SEQ_L; t0 += SCH) {
        #pragma unroll
        for (int i = 0; i < 2; i++) {
            const int idx = tid + i * 256;
            const int tt = idx >> 4;
            const int col = idx & 15;
            const size_t row = (size_t)(b * SEQ_L + t0 + tt);
            dt_s[tt][col] = dt[row * D_INNER + d0 + col];
            u_s[tt][col]  = xc[row * D_INNER + d0 + col];
            z_s[tt][col]  = xz[row * (2 * D_INNER) + D_INNER + d0 + col];
            B_s[tt][col]  = dbc[row * DBC_N + DT_RANK + col];
            C_s[tt][col]  = dbc[row * DBC_N + DT_RANK + D_STATE + col];
        }
        __syncthreads();

        for (int tt = 0; tt < SCH; tt++) {
            const float dtv = dt_s[tt][dl];
            const float uv = u_s[tt][dl];
            const float a = __expf(dtv * Adn);
            h = fmaf(a, h, dtv * uv * B_s[tt][n]);
            float yp = h * C_s[tt][n];
            yp += __shfl_xor(yp, 1);
            yp += __shfl_xor(yp, 2);
            yp += __shfl_xor(yp, 4);
            yp += __shfl_xor(yp, 8);
            if (n == 0) {
                const float zv = z_s[tt][dl];
                const float sig = 1.f / (1.f + __expf(-zv));
                y[(size_t)(b * SEQ_L + t0 + tt) * D_INNER + d] =
                    (__bf16)((yp + Dd * uv) * (zv * sig));
            }
        }
        __syncthreads();
    }
}

// ---------------------------------------------------------------------------
// Final LayerNorm over D_MODEL=1024. 256 thr per token row.
// ---------------------------------------------------------------------------
__global__ __launch_bounds__(256) void layernorm_kernel(
    const float* __restrict__ x, const float* __restrict__ w,
    const float* __restrict__ bb, float* __restrict__ out)
{
    __shared__ float red[8];
    const int row = blockIdx.x;
    const float* xr = x + (size_t)row * D_MODEL;
    const int tid = threadIdx.x;

    float v[4];
    float s = 0.f;
    #pragma unroll
    for (int i = 0; i < 4; i++) { v[i] = xr[tid + i * 256]; s += v[i]; }
    #pragma unroll
    for (int off = 32; off >= 1; off >>= 1) s += __shfl_xor(s, off);
    const int wid = tid >> 6;
    if ((tid & 63) == 0) red[wid] = s;
    __syncthreads();
    const float mu = (red[0] + red[1] + red[2] + red[3]) * (1.f / D_MODEL);

    float vs = 0.f;
    #pragma unroll
    for (int i = 0; i < 4; i++) { const float dd = v[i] - mu; vs = fmaf(dd, dd, vs); }
    #pragma unroll
    for (int off = 32; off >= 1; off >>= 1) vs += __shfl_xor(vs, off);
    if ((tid & 63) == 0) red[4 + wid] = vs;
    __syncthreads();
    const float var = (red[4] + red[5] + red[6] + red[7]) * (1.f / D_MODEL);
    const float inv = rsqrtf(var + EPS_LN);

    #pragma unroll
    for (int i = 0; i < 4; i++) {
        const int c = tid + i * 256;
        out[(size_t)row * D_MODEL + c] = (v[i] - mu) * inv * w[c] + bb[c];
    }
}

// ---------------------------------------------------------------------------
extern "C" void kernel_launch(void* const* d_in, const int* in_sizes, int n_in,
                              void* d_out, int out_size, void* d_ws, size_t ws_size,
                              hipStream_t stream)
{
    const float* x_in   = (const float*)d_in[0];
    const float* W_in   = (const float*)d_in[1];
    const float* conv_w = (const float*)d_in[2];
    const float* conv_b = (const float*)d_in[3];
    const float* W_x    = (const float*)d_in[4];
    const float* W_dt   = (const float*)d_in[5];
    const float* b_dt   = (const float*)d_in[6];
    const float* A_log  = (const float*)d_in[7];
    const float* D_skip = (const float*)d_in[8];
    const float* W_out  = (const float*)d_in[9];
    const float* ln_w   = (const float*)d_in[10];
    const float* ln_b   = (const float*)d_in[11];
    float* out = (float*)d_out;

    // fp32 workspace
    float* buf_x   = (float*)d_ws;                              // 4M
    float* buf_xz  = buf_x  + (size_t)NROWS * D_MODEL;          // 16M
    float* buf_xc  = buf_xz + (size_t)NROWS * 2 * D_INNER;      // 8M
    float* buf_dbc = buf_xc + (size_t)NROWS * D_INNER;          // 0.4M
    float* buf_dt  = buf_dbc + (size_t)NROWS * DBC_N;           // 8M
    // bf16 workspace
    __bf16* xbf    = (__bf16*)(buf_dt + (size_t)NROWS * D_INNER);
    __bf16* ybf    = xbf + (size_t)NROWS * D_MODEL;
    __bf16* Win_bf = ybf + (size_t)NROWS * D_INNER;
    __bf16* Wout_bf = Win_bf + (size_t)(2 * D_INNER) * D_MODEL;

    const dim3 blk(256);
    const int n_el = NROWS * D_INNER;

    // one-time casts (per call)
    cast_bf16_kernel<<<(2 * D_INNER * D_MODEL) / 1024, blk, 0, stream>>>(
        W_in, Win_bf, 2 * D_INNER * D_MODEL);
    cast_bf16_kernel<<<(D_MODEL * D_INNER) / 1024, blk, 0, stream>>>(
        W_out, Wout_bf, D_MODEL * D_INNER);
    cast_bf16_kernel<<<(NROWS * D_MODEL) / 1024, blk, 0, stream>>>(
        x_in, xbf, NROWS * D_MODEL);
    hipMemcpyAsync(buf_x, x_in, (size_t)NROWS * D_MODEL * sizeof(float),
                   hipMemcpyDeviceToDevice, stream);

    for (int layer = 0; layer < N_LAYERS; layer++) {
        // xz = x @ W_in^T   (M=4096, N=4096, K=1024) — bf16 MFMA
        gemm_mfma_nt<false><<<dim3(2 * D_INNER / 128, NROWS / 128), blk, 0, stream>>>(
            xbf, Win_bf, buf_xz, nullptr, nullptr, NROWS, 2 * D_INNER, D_MODEL);
        // conv + silu -> xc (fp32)
        conv_silu_kernel<<<(n_el + 255) / 256, blk, 0, stream>>>(
            buf_xz, conv_w, conv_b, buf_xc);
        // dbc = xc @ W_x^T  (M=4096, N=97, K=2048) — fp32
        gemm_nt<<<dim3((DBC_N + BN - 1) / BN, NROWS / BM), blk, 0, stream>>>(
            buf_xc, W_x, buf_dbc, nullptr, NROWS, DBC_N, D_INNER, D_INNER, D_INNER);
        // dt_lin = dt_low @ W_dt^T  (M=4096, N=2048, K=65) — fp32
        gemm_nt<<<dim3(D_INNER / BN, NROWS / BM), blk, 0, stream>>>(
            buf_dbc, W_dt, buf_dt, nullptr, NROWS, D_INNER, DT_RANK, DBC_N, DT_RANK);
        softplus_bias_kernel<<<(n_el + 255) / 256, blk, 0, stream>>>(
            buf_dt, b_dt, buf_dt);
        // selective scan + gating -> y (bf16)
        scan_kernel<<<dim3(D_INNER / 16, B_SZ), blk, 0, stream>>>(
            buf_dt, buf_dbc, buf_xc, buf_xz, A_log, D_skip, ybf);
        // x = y @ W_out^T + x  (M=4096, N=1024, K=2048) — bf16 MFMA,
        // fused residual + bf16 copy for next layer's GEMM1
        gemm_mfma_nt<true><<<dim3(D_MODEL / 128, NROWS / 128), blk, 0, stream>>>(
            ybf, Wout_bf, buf_x, buf_x, xbf, NROWS, D_MODEL, D_INNER);
    }

    layernorm_kernel<<<NROWS, blk, 0, stream>>>(buf_x, ln_w, ln_b, out);
}

// Round 3
// 2253.795 us; speedup vs baseline: 3.7537x; 1.8239x over previous
//
#include <hip/hip_runtime.h>
#include <hip/hip_bf16.h>
#include <math.h>

// Problem constants
#define D_MODEL 1024
#define N_LAYERS 4
#define D_STATE 16
#define D_CONV 4
#define D_INNER 2048
#define DT_RANK 65
#define B_SZ 2
#define SEQ_L 2048
#define EPS_LN 1e-5f

#define NROWS (B_SZ * SEQ_L)          // 4096 token rows
#define DBC_N (DT_RANK + 2 * D_STATE) // 97

// scan chunking
#define NC 64                         // chunks over L
#define LC (SEQ_L / NC)               // 32 steps per chunk

typedef __bf16 bf16x8 __attribute__((ext_vector_type(8)));
typedef float floatx4 __attribute__((ext_vector_type(4)));

// ---------------------------------------------------------------------------
// async global->LDS 16B per lane. LDS dest is wave-uniform base + lane*16.
// ---------------------------------------------------------------------------
__device__ __forceinline__ void async_copy16(const void* gsrc, void* lds_dst)
{
    __builtin_amdgcn_global_load_lds(
        (const __attribute__((address_space(1))) void*)gsrc,
        (__attribute__((address_space(3))) void*)lds_dst,
        16, 0, 0);
}

// ---------------------------------------------------------------------------
// MFMA bf16 GEMM (NT): C[m,n] = sum_k A[m*K+k]*B[n*K+k]  (A:MxK, B:NxK bf16)
// 128x128 tile, BK=32, 256 threads = 4 waves (2x2 of 64x64), 16x16x32 MFMA.
// FUSE: C = acc + Cres (fp32) and also writes bf16 copy to Cbf.
// ---------------------------------------------------------------------------
template <bool FUSE>
__global__ __launch_bounds__(256) void gemm_mfma_nt(
    const __bf16* __restrict__ A, const __bf16* __restrict__ B,
    float* __restrict__ C, const float* __restrict__ Cres,
    __bf16* __restrict__ Cbf, int M, int N, int K)
{
    __shared__ __bf16 As[128 * 32];
    __shared__ __bf16 Bs[128 * 32];

    const int tid = threadIdx.x;
    const int lane = tid & 63;
    const int w = tid >> 6;
    const int wm = w & 1;
    const int wn = w >> 1;
    const int m0 = blockIdx.y * 128;
    const int n0 = blockIdx.x * 128;

    const int lrow = lane >> 2;
    const int lcol8 = (lane & 3) * 8;
    const int fr = lane & 15;
    const int fk = (lane >> 4) * 8;

    floatx4 acc[4][4];
    #pragma unroll
    for (int i = 0; i < 4; i++)
        #pragma unroll
        for (int j = 0; j < 4; j++)
            acc[i][j] = floatx4{0.f, 0.f, 0.f, 0.f};

    for (int k0 = 0; k0 < K; k0 += 32) {
        #pragma unroll
        for (int g2 = 0; g2 < 2; g2++) {
            const int g = w * 2 + g2;
            const __bf16* ga = A + (size_t)(m0 + g * 16 + lrow) * K + k0 + lcol8;
            async_copy16(ga, &As[g * 512]);
            const __bf16* gb = B + (size_t)(n0 + g * 16 + lrow) * K + k0 + lcol8;
            async_copy16(gb, &Bs[g * 512]);
        }
        __syncthreads();

        bf16x8 af[4], bf[4];
        #pragma unroll
        for (int i = 0; i < 4; i++)
            af[i] = *(const bf16x8*)&As[(wm * 64 + i * 16 + fr) * 32 + fk];
        #pragma unroll
        for (int j = 0; j < 4; j++)
            bf[j] = *(const bf16x8*)&Bs[(wn * 64 + j * 16 + fr) * 32 + fk];

        #pragma unroll
        for (int i = 0; i < 4; i++)
            #pragma unroll
            for (int j = 0; j < 4; j++)
                acc[i][j] = __builtin_amdgcn_mfma_f32_16x16x32_bf16(
                    af[i], bf[j], acc[i][j], 0, 0, 0);

        __syncthreads();
    }

    const int crow = (lane >> 4) * 4;
    const int ccol = lane & 15;
    #pragma unroll
    for (int i = 0; i < 4; i++) {
        #pragma unroll
        for (int j = 0; j < 4; j++) {
            #pragma unroll
            for (int r = 0; r < 4; r++) {
                const int gm = m0 + wm * 64 + i * 16 + crow + r;
                const int gn = n0 + wn * 64 + j * 16 + ccol;
                float v = acc[i][j][r];
                if (FUSE) {
                    v += Cres[(size_t)gm * N + gn];
                    Cbf[(size_t)gm * N + gn] = (__bf16)v;
                }
                C[(size_t)gm * N + gn] = v;
            }
        }
    }
}

// ---------------------------------------------------------------------------
// fp32 NT GEMM for the small matmuls (N=97 / K=65). 64x64 tile, BK=16.
// SOFTPLUS: epilogue applies softplus(v + bias[n]).
// ---------------------------------------------------------------------------
#define BM 64
#define BN 64
#define BK 16
template <bool SOFTPLUS>
__global__ __launch_bounds__(256) void gemm_nt(
    const float* __restrict__ A, const float* __restrict__ B,
    float* __restrict__ C, const float* __restrict__ bias,
    int M, int N, int K, int lda, int ldb)
{
    __shared__ float As[BK][BM + 4];
    __shared__ float Bs[BK][BN + 4];

    const int m0 = blockIdx.y * BM;
    const int n0 = blockIdx.x * BN;
    const int tid = threadIdx.x;
    const int tx = tid & 15;
    const int ty = tid >> 4;

    float acc[4][4] = {};

    for (int k0 = 0; k0 < K; k0 += BK) {
        const int c = tid & 15;
        const int rbase = tid >> 4;
        #pragma unroll
        for (int i = 0; i < 4; i++) {
            const int r = rbase + i * 16;
            const int gk = k0 + c;
            const int gm = m0 + r;
            const int gn = n0 + r;
            As[c][r] = (gm < M && gk < K) ? A[(size_t)gm * lda + gk] : 0.f;
            Bs[c][r] = (gn < N && gk < K) ? B[(size_t)gn * ldb + gk] : 0.f;
        }
        __syncthreads();

        #pragma unroll
        for (int k = 0; k < BK; k++) {
            float a[4], b[4];
            #pragma unroll
            for (int i = 0; i < 4; i++) a[i] = As[k][ty * 4 + i];
            #pragma unroll
            for (int j = 0; j < 4; j++) b[j] = Bs[k][tx * 4 + j];
            #pragma unroll
            for (int i = 0; i < 4; i++)
                #pragma unroll
                for (int j = 0; j < 4; j++)
                    acc[i][j] = fmaf(a[i], b[j], acc[i][j]);
        }
        __syncthreads();
    }

    #pragma unroll
    for (int i = 0; i < 4; i++) {
        const int gm = m0 + ty * 4 + i;
        if (gm >= M) continue;
        #pragma unroll
        for (int j = 0; j < 4; j++) {
            const int gn = n0 + tx * 4 + j;
            if (gn < N) {
                float v = acc[i][j];
                if (SOFTPLUS) {
                    v += bias[gn];
                    v = fmaxf(v, 0.f) + log1pf(__expf(-fabsf(v)));
                }
                C[(size_t)gm * N + gn] = v;
            }
        }
    }
}

// ---------------------------------------------------------------------------
// fp32 -> bf16 cast, 4 elems/thread
// ---------------------------------------------------------------------------
__global__ __launch_bounds__(256) void cast_bf16_kernel(
    const float* __restrict__ in, __bf16* __restrict__ out, int n)
{
    const int i = (blockIdx.x * 256 + threadIdx.x) * 4;
    if (i >= n) return;
    const float4 v = *(const float4*)(in + i);
    out[i + 0] = (__bf16)v.x;
    out[i + 1] = (__bf16)v.y;
    out[i + 2] = (__bf16)v.z;
    out[i + 3] = (__bf16)v.w;
}

// ---------------------------------------------------------------------------
// Depthwise causal conv (D_CONV=4) + bias + SiLU.
// ---------------------------------------------------------------------------
__global__ __launch_bounds__(256) void conv_silu_kernel(
    const float* __restrict__ xz, const float* __restrict__ conv_w,
    const float* __restrict__ conv_b, float* __restrict__ xc)
{
    const size_t idx = (size_t)blockIdx.x * 256 + threadIdx.x;
    if (idx >= (size_t)NROWS * D_INNER) return;
    const int d = (int)(idx & (D_INNER - 1));
    const size_t bt = idx >> 11;
    const int t = (int)(bt & (SEQ_L - 1));

    float acc = conv_b[d];
    #pragma unroll
    for (int j = 0; j < D_CONV; j++) {
        const int tt = t + j - (D_CONV - 1);
        if (tt >= 0) {
            const long row = (long)bt + j - (D_CONV - 1);
            acc = fmaf(xz[(size_t)row * (2 * D_INNER) + d], conv_w[d * D_CONV + j], acc);
        }
    }
    xc[idx] = acc / (1.f + __expf(-acc));
}

// ---------------------------------------------------------------------------
// Chunk-parallel selective scan.
// Pass 1: per (b, chunk, d) thread: 16 states in regs, compute
//         P_n = prod_t a_n(t), S_n = local scan from h=0.
// grid (D_INNER/256, NC, B).
// ---------------------------------------------------------------------------
__global__ __launch_bounds__(256) void scan_p1(
    const float* __restrict__ dt, const float* __restrict__ dbc,
    const float* __restrict__ xc, const float* __restrict__ A_log,
    float* __restrict__ P, float* __restrict__ S)
{
    const int d = blockIdx.x * 256 + threadIdx.x;
    const int c = blockIdx.y;
    const int b = blockIdx.z;
    const int t0 = c * LC;

    __shared__ float Bs[LC][16];
    #pragma unroll
    for (int r = 0; r < 2; r++) {
        const int idx = threadIdx.x + r * 256;   // 0..511
        const int tt = idx >> 4, n = idx & 15;
        Bs[tt][n] = dbc[(size_t)(b * SEQ_L + t0 + tt) * DBC_N + DT_RANK + n];
    }
    __syncthreads();

    float A[16], h[16], Pr[16];
    #pragma unroll
    for (int n = 0; n < 16; n++) {
        A[n] = -__expf(A_log[d * D_STATE + n]);
        h[n] = 0.f;
        Pr[n] = 1.f;
    }

    for (int t = 0; t < LC; t++) {
        const size_t row = (size_t)(b * SEQ_L + t0 + t);
        const float dtv = dt[row * D_INNER + d];
        const float uv = xc[row * D_INNER + d];
        const float dtu = dtv * uv;
        #pragma unroll
        for (int n = 0; n < 16; n++) {
            const float a = __expf(dtv * A[n]);
            h[n] = fmaf(a, h[n], dtu * Bs[t][n]);
            Pr[n] *= a;
        }
    }

    const size_t base = ((size_t)(b * NC + c) * D_STATE) * D_INNER + d;
    #pragma unroll
    for (int n = 0; n < 16; n++) {
        P[base + (size_t)n * D_INNER] = Pr[n];
        S[base + (size_t)n * D_INNER] = h[n];
    }
}

// ---------------------------------------------------------------------------
// Pass 2: sequential combine over chunks per (b,n,d) lane.
// Writes h_in for each chunk IN PLACE over P (read-before-write per idx).
// ---------------------------------------------------------------------------
__global__ __launch_bounds__(256) void scan_p2(
    float* __restrict__ P, const float* __restrict__ S)
{
    const size_t g = (size_t)blockIdx.x * 256 + threadIdx.x;
    const int d = (int)(g & (D_INNER - 1));
    const int n = (int)((g >> 11) & 15);
    const int b = (int)(g >> 15);

    float h = 0.f;
    for (int c = 0; c < NC; c++) {
        const size_t idx = ((size_t)(b * NC + c) * D_STATE + n) * D_INNER + d;
        const float p = P[idx];
        const float s = S[idx];
        P[idx] = h;              // h_in for this chunk
        h = fmaf(p, h, s);
    }
}

// ---------------------------------------------------------------------------
// Pass 3: recompute local scan seeded with h_in (now in P), produce
//         y = (sum_n h_n*C_n + D*u) * silu(z)  -> bf16
// ---------------------------------------------------------------------------
__global__ __launch_bounds__(256) void scan_p3(
    const float* __restrict__ dt, const float* __restrict__ dbc,
    const float* __restrict__ xc, const float* __restrict__ xz,
    const float* __restrict__ A_log, const float* __restrict__ D_skip,
    const float* __restrict__ Hin, __bf16* __restrict__ y)
{
    const int d = blockIdx.x * 256 + threadIdx.x;
    const int c = blockIdx.y;
    const int b = blockIdx.z;
    const int t0 = c * LC;

    __shared__ float Bs[LC][16], Cs[LC][16];
    #pragma unroll
    for (int r = 0; r < 2; r++) {
        const int idx = threadIdx.x + r * 256;   // 0..511
        const int tt = idx >> 4, n = idx & 15;
        const size_t rowoff = (size_t)(b * SEQ_L + t0 + tt) * DBC_N + DT_RANK;
        Bs[tt][n] = dbc[rowoff + n];
        Cs[tt][n] = dbc[rowoff + D_STATE + n];
    }
    __syncthreads();

    float A[16], h[16];
    const size_t base = ((size_t)(b * NC + c) * D_STATE) * D_INNER + d;
    #pragma unroll
    for (int n = 0; n < 16; n++) {
        A[n] = -__expf(A_log[d * D_STATE + n]);
        h[n] = Hin[base + (size_t)n * D_INNER];
    }
    const float Dd = D_skip[d];

    for (int t = 0; t < LC; t++) {
        const size_t row = (size_t)(b * SEQ_L + t0 + t);
        const float dtv = dt[row * D_INNER + d];
        const float uv = xc[row * D_INNER + d];
        const float dtu = dtv * uv;
        float yp = 0.f;
        #pragma unroll
        for (int n = 0; n < 16; n++) {
            const float a = __expf(dtv * A[n]);
            h[n] = fmaf(a, h[n], dtu * Bs[t][n]);
            yp = fmaf(h[n], Cs[t][n], yp);
        }
        const float zv = xz[row * (2 * D_INNER) + D_INNER + d];
        const float sig = 1.f / (1.f + __expf(-zv));
        y[row * D_INNER + d] = (__bf16)((yp + Dd * uv) * (zv * sig));
    }
}

// ---------------------------------------------------------------------------
// Final LayerNorm over D_MODEL=1024. 256 thr per token row.
// ---------------------------------------------------------------------------
__global__ __launch_bounds__(256) void layernorm_kernel(
    const float* __restrict__ x, const float* __restrict__ w,
    const float* __restrict__ bb, float* __restrict__ out)
{
    __shared__ float red[8];
    const int row = blockIdx.x;
    const float* xr = x + (size_t)row * D_MODEL;
    const int tid = threadIdx.x;

    float v[4];
    float s = 0.f;
    #pragma unroll
    for (int i = 0; i < 4; i++) { v[i] = xr[tid + i * 256]; s += v[i]; }
    #pragma unroll
    for (int off = 32; off >= 1; off >>= 1) s += __shfl_xor(s, off);
    const int wid = tid >> 6;
    if ((tid & 63) == 0) red[wid] = s;
    __syncthreads();
    const float mu = (red[0] + red[1] + red[2] + red[3]) * (1.f / D_MODEL);

    float vs = 0.f;
    #pragma unroll
    for (int i = 0; i < 4; i++) { const float dd = v[i] - mu; vs = fmaf(dd, dd, vs); }
    #pragma unroll
    for (int off = 32; off >= 1; off >>= 1) vs += __shfl_xor(vs, off);
    if ((tid & 63) == 0) red[4 + wid] = vs;
    __syncthreads();
    const float var = (red[4] + red[5] + red[6] + red[7]) * (1.f / D_MODEL);
    const float inv = rsqrtf(var + EPS_LN);

    #pragma unroll
    for (int i = 0; i < 4; i++) {
        const int c = tid + i * 256;
        out[(size_t)row * D_MODEL + c] = (v[i] - mu) * inv * w[c] + bb[c];
    }
}

// ---------------------------------------------------------------------------
extern "C" void kernel_launch(void* const* d_in, const int* in_sizes, int n_in,
                              void* d_out, int out_size, void* d_ws, size_t ws_size,
                              hipStream_t stream)
{
    const float* x_in   = (const float*)d_in[0];
    const float* W_in   = (const float*)d_in[1];
    const float* conv_w = (const float*)d_in[2];
    const float* conv_b = (const float*)d_in[3];
    const float* W_x    = (const float*)d_in[4];
    const float* W_dt   = (const float*)d_in[5];
    const float* b_dt   = (const float*)d_in[6];
    const float* A_log  = (const float*)d_in[7];
    const float* D_skip = (const float*)d_in[8];
    const float* W_out  = (const float*)d_in[9];
    const float* ln_w   = (const float*)d_in[10];
    const float* ln_b   = (const float*)d_in[11];
    float* out = (float*)d_out;

    // fp32 workspace
    float* buf_x   = (float*)d_ws;                              // 16 MB
    float* buf_xz  = buf_x  + (size_t)NROWS * D_MODEL;          // 64 MB
    float* buf_xc  = buf_xz + (size_t)NROWS * 2 * D_INNER;      // 32 MB
    float* buf_dbc = buf_xc + (size_t)NROWS * D_INNER;          // 1.6 MB
    float* buf_dt  = buf_dbc + (size_t)NROWS * DBC_N;           // 32 MB
    float* buf_P   = buf_dt + (size_t)NROWS * D_INNER;          // 16 MB
    float* buf_S   = buf_P + (size_t)B_SZ * NC * D_STATE * D_INNER; // 16 MB
    // bf16 workspace
    __bf16* xbf    = (__bf16*)(buf_S + (size_t)B_SZ * NC * D_STATE * D_INNER);
    __bf16* ybf    = xbf + (size_t)NROWS * D_MODEL;
    __bf16* Win_bf = ybf + (size_t)NROWS * D_INNER;
    __bf16* Wout_bf = Win_bf + (size_t)(2 * D_INNER) * D_MODEL;

    const dim3 blk(256);
    const int n_el = NROWS * D_INNER;

    cast_bf16_kernel<<<(2 * D_INNER * D_MODEL) / 1024, blk, 0, stream>>>(
        W_in, Win_bf, 2 * D_INNER * D_MODEL);
    cast_bf16_kernel<<<(D_MODEL * D_INNER) / 1024, blk, 0, stream>>>(
        W_out, Wout_bf, D_MODEL * D_INNER);
    cast_bf16_kernel<<<(NROWS * D_MODEL) / 1024, blk, 0, stream>>>(
        x_in, xbf, NROWS * D_MODEL);
    hipMemcpyAsync(buf_x, x_in, (size_t)NROWS * D_MODEL * sizeof(float),
                   hipMemcpyDeviceToDevice, stream);

    for (int layer = 0; layer < N_LAYERS; layer++) {
        // xz = x @ W_in^T   (4096x4096x1024) — bf16 MFMA
        gemm_mfma_nt<false><<<dim3(2 * D_INNER / 128, NROWS / 128), blk, 0, stream>>>(
            xbf, Win_bf, buf_xz, nullptr, nullptr, NROWS, 2 * D_INNER, D_MODEL);
        // conv + silu -> xc (fp32)
        conv_silu_kernel<<<(n_el + 255) / 256, blk, 0, stream>>>(
            buf_xz, conv_w, conv_b, buf_xc);
        // dbc = xc @ W_x^T  (4096x97x2048) — fp32
        gemm_nt<false><<<dim3((DBC_N + BN - 1) / BN, NROWS / BM), blk, 0, stream>>>(
            buf_xc, W_x, buf_dbc, nullptr, NROWS, DBC_N, D_INNER, D_INNER, D_INNER);
        // dt = softplus(dt_low @ W_dt^T + b_dt)  (4096x2048x65) — fp32, fused
        gemm_nt<true><<<dim3(D_INNER / BN, NROWS / BM), blk, 0, stream>>>(
            buf_dbc, W_dt, buf_dt, b_dt, NROWS, D_INNER, DT_RANK, DBC_N, DT_RANK);
        // chunk-parallel scan
        scan_p1<<<dim3(D_INNER / 256, NC, B_SZ), blk, 0, stream>>>(
            buf_dt, buf_dbc, buf_xc, A_log, buf_P, buf_S);
        scan_p2<<<(B_SZ * D_STATE * D_INNER) / 256, blk, 0, stream>>>(
            buf_P, buf_S);
        scan_p3<<<dim3(D_INNER / 256, NC, B_SZ), blk, 0, stream>>>(
            buf_dt, buf_dbc, buf_xc, buf_xz, A_log, D_skip, buf_P, ybf);
        // x = y @ W_out^T + x  (4096x1024x2048) — bf16 MFMA, fused residual+cast
        gemm_mfma_nt<true><<<dim3(D_MODEL / 128, NROWS / 128), blk, 0, stream>>>(
            ybf, Wout_bf, buf_x, buf_x, xbf, NROWS, D_MODEL, D_INNER);
    }

    layernorm_kernel<<<NROWS, blk, 0, stream>>>(buf_x, ln_w, ln_b, out);
}

// Round 4
// 1261.460 us; speedup vs baseline: 6.7066x; 1.7867x over previous
//
#include <hip/hip_runtime.h>
#include <hip/hip_bf16.h>
#include <math.h>

// Problem constants
#define D_MODEL 1024
#define N_LAYERS 4
#define D_STATE 16
#define D_CONV 4
#define D_INNER 2048
#define DT_RANK 65
#define B_SZ 2
#define SEQ_L 2048
#define EPS_LN 1e-5f

#define NROWS (B_SZ * SEQ_L)          // 4096 token rows
#define DBC_LD 128                    // padded row stride for dbc (97 -> 128)
#define KDT 96                        // padded K for dt GEMM (65 -> 96)

// scan chunking
#define NC 64
#define LC (SEQ_L / NC)               // 32

typedef __bf16 bf16x8 __attribute__((ext_vector_type(8)));
typedef float floatx4 __attribute__((ext_vector_type(4)));

// ---------------------------------------------------------------------------
__device__ __forceinline__ void async_copy16(const void* gsrc, void* lds_dst)
{
    __builtin_amdgcn_global_load_lds(
        (const __attribute__((address_space(1))) void*)gsrc,
        (__attribute__((address_space(3))) void*)lds_dst,
        16, 0, 0);
}

// ---------------------------------------------------------------------------
// MFMA bf16 GEMM (NT): C[m,n] = sum_k A[m*lda+k]*B[n*ldb+k]
// 128x128 tile, BK=32, 256 threads = 4 waves (2x2 of 64x64), 16x16x32 MFMA.
// Epilogues: 0 = plain fp32 store
//            1 = += Cres, store fp32 + bf16 copy (GEMM4 fused residual)
//            2 = atomicAdd fp32 (split-K; blockIdx.z picks K-slice of ksl)
//            3 = softplus(v + bias[n]) fp32 store (dt GEMM)
// Requires M%128==0, N%128==0, K%32==0, 16B-aligned rows.
// ---------------------------------------------------------------------------
template <int EPI>
__global__ __launch_bounds__(256) void gemm_mfma_nt(
    const __bf16* __restrict__ A, const __bf16* __restrict__ B,
    float* __restrict__ C, const float* __restrict__ Cres,
    __bf16* __restrict__ Cbf, const float* __restrict__ bias,
    int M, int N, int K, int lda, int ldb, int ldc, int ksl)
{
    __shared__ __bf16 As[128 * 32];
    __shared__ __bf16 Bs[128 * 32];

    const int tid = threadIdx.x;
    const int lane = tid & 63;
    const int w = tid >> 6;
    const int wm = w & 1;
    const int wn = w >> 1;
    const int m0 = blockIdx.y * 128;
    const int n0 = blockIdx.x * 128;

    const int lrow = lane >> 2;
    const int lcol8 = (lane & 3) * 8;
    const int fr = lane & 15;
    const int fk = (lane >> 4) * 8;

    floatx4 acc[4][4];
    #pragma unroll
    for (int i = 0; i < 4; i++)
        #pragma unroll
        for (int j = 0; j < 4; j++)
            acc[i][j] = floatx4{0.f, 0.f, 0.f, 0.f};

    const int kbeg = blockIdx.z * ksl;
    const int kend = (kbeg + ksl < K) ? (kbeg + ksl) : K;

    for (int k0 = kbeg; k0 < kend; k0 += 32) {
        #pragma unroll
        for (int g2 = 0; g2 < 2; g2++) {
            const int g = w * 2 + g2;
            const __bf16* ga = A + (size_t)(m0 + g * 16 + lrow) * lda + k0 + lcol8;
            async_copy16(ga, &As[g * 512]);
            const __bf16* gb = B + (size_t)(n0 + g * 16 + lrow) * ldb + k0 + lcol8;
            async_copy16(gb, &Bs[g * 512]);
        }
        __syncthreads();

        bf16x8 af[4], bf[4];
        #pragma unroll
        for (int i = 0; i < 4; i++)
            af[i] = *(const bf16x8*)&As[(wm * 64 + i * 16 + fr) * 32 + fk];
        #pragma unroll
        for (int j = 0; j < 4; j++)
            bf[j] = *(const bf16x8*)&Bs[(wn * 64 + j * 16 + fr) * 32 + fk];

        #pragma unroll
        for (int i = 0; i < 4; i++)
            #pragma unroll
            for (int j = 0; j < 4; j++)
                acc[i][j] = __builtin_amdgcn_mfma_f32_16x16x32_bf16(
                    af[i], bf[j], acc[i][j], 0, 0, 0);

        __syncthreads();
    }

    const int crow = (lane >> 4) * 4;
    const int ccol = lane & 15;
    #pragma unroll
    for (int i = 0; i < 4; i++) {
        #pragma unroll
        for (int j = 0; j < 4; j++) {
            #pragma unroll
            for (int r = 0; r < 4; r++) {
                const int gm = m0 + wm * 64 + i * 16 + crow + r;
                const int gn = n0 + wn * 64 + j * 16 + ccol;
                float v = acc[i][j][r];
                const size_t ci = (size_t)gm * ldc + gn;
                if (EPI == 0) {
                    C[ci] = v;
                } else if (EPI == 1) {
                    v += Cres[ci];
                    C[ci] = v;
                    Cbf[ci] = (__bf16)v;
                } else if (EPI == 2) {
                    atomicAdd(&C[ci], v);
                } else {  // EPI == 3
                    v += bias[gn];
                    v = fmaxf(v, 0.f) + log1pf(__expf(-fabsf(v)));
                    C[ci] = v;
                }
            }
        }
    }
}

// ---------------------------------------------------------------------------
// fp32 -> bf16 cast, 4 elems/thread (n % 1024 == 0)
// ---------------------------------------------------------------------------
__global__ __launch_bounds__(256) void cast_bf16_kernel(
    const float* __restrict__ in, __bf16* __restrict__ out, int n)
{
    const int i = (blockIdx.x * 256 + threadIdx.x) * 4;
    if (i >= n) return;
    const float4 v = *(const float4*)(in + i);
    out[i + 0] = (__bf16)v.x;
    out[i + 1] = (__bf16)v.y;
    out[i + 2] = (__bf16)v.z;
    out[i + 3] = (__bf16)v.w;
}

// ---------------------------------------------------------------------------
// pad-cast: out[r*C_out+c] = (r<R_in && c<C_in) ? (bf16)in[r*C_in+c] : 0
// ---------------------------------------------------------------------------
__global__ __launch_bounds__(256) void pad_cast_kernel(
    const float* __restrict__ in, __bf16* __restrict__ out,
    int R_out, int C_out, int R_in, int C_in)
{
    const int i = blockIdx.x * 256 + threadIdx.x;
    if (i >= R_out * C_out) return;
    const int r = i / C_out;
    const int c = i - r * C_out;
    out[i] = (r < R_in && c < C_in) ? (__bf16)in[r * C_in + c] : (__bf16)0.f;
}

// ---------------------------------------------------------------------------
// Depthwise causal conv (D_CONV=4) + bias + SiLU -> bf16 xc
// ---------------------------------------------------------------------------
__global__ __launch_bounds__(256) void conv_silu_kernel(
    const float* __restrict__ xz, const float* __restrict__ conv_w,
    const float* __restrict__ conv_b, __bf16* __restrict__ xc)
{
    const size_t idx = (size_t)blockIdx.x * 256 + threadIdx.x;
    if (idx >= (size_t)NROWS * D_INNER) return;
    const int d = (int)(idx & (D_INNER - 1));
    const size_t bt = idx >> 11;
    const int t = (int)(bt & (SEQ_L - 1));

    float acc = conv_b[d];
    #pragma unroll
    for (int j = 0; j < D_CONV; j++) {
        const int tt = t + j - (D_CONV - 1);
        if (tt >= 0) {
            const long row = (long)bt + j - (D_CONV - 1);
            acc = fmaf(xz[(size_t)row * (2 * D_INNER) + d], conv_w[d * D_CONV + j], acc);
        }
    }
    xc[idx] = (__bf16)(acc / (1.f + __expf(-acc)));
}

// ---------------------------------------------------------------------------
// Chunk-parallel selective scan.
// Pass 1: per (b, chunk, d) thread: P_n = prod a, S_n = local scan from 0.
// ---------------------------------------------------------------------------
__global__ __launch_bounds__(256) void scan_p1(
    const float* __restrict__ dt, const float* __restrict__ dbc,
    const __bf16* __restrict__ xc, const float* __restrict__ A_log,
    float* __restrict__ P, float* __restrict__ S)
{
    const int d = blockIdx.x * 256 + threadIdx.x;
    const int c = blockIdx.y;
    const int b = blockIdx.z;
    const int t0 = c * LC;

    __shared__ float Bs[LC][16];
    #pragma unroll
    for (int r = 0; r < 2; r++) {
        const int idx = threadIdx.x + r * 256;
        const int tt = idx >> 4, n = idx & 15;
        Bs[tt][n] = dbc[(size_t)(b * SEQ_L + t0 + tt) * DBC_LD + DT_RANK + n];
    }
    __syncthreads();

    float A[16], h[16], Pr[16];
    #pragma unroll
    for (int n = 0; n < 16; n++) {
        A[n] = -__expf(A_log[d * D_STATE + n]);
        h[n] = 0.f;
        Pr[n] = 1.f;
    }

    for (int t = 0; t < LC; t++) {
        const size_t row = (size_t)(b * SEQ_L + t0 + t);
        const float dtv = dt[row * D_INNER + d];
        const float uv = (float)xc[row * D_INNER + d];
        const float dtu = dtv * uv;
        #pragma unroll
        for (int n = 0; n < 16; n++) {
            const float a = __expf(dtv * A[n]);
            h[n] = fmaf(a, h[n], dtu * Bs[t][n]);
            Pr[n] *= a;
        }
    }

    const size_t base = ((size_t)(b * NC + c) * D_STATE) * D_INNER + d;
    #pragma unroll
    for (int n = 0; n < 16; n++) {
        P[base + (size_t)n * D_INNER] = Pr[n];
        S[base + (size_t)n * D_INNER] = h[n];
    }
}

// ---------------------------------------------------------------------------
// Pass 2: sequential combine over chunks; h_in written in place over P.
// ---------------------------------------------------------------------------
__global__ __launch_bounds__(256) void scan_p2(
    float* __restrict__ P, const float* __restrict__ S)
{
    const size_t g = (size_t)blockIdx.x * 256 + threadIdx.x;
    const int d = (int)(g & (D_INNER - 1));
    const int n = (int)((g >> 11) & 15);
    const int b = (int)(g >> 15);

    float h = 0.f;
    for (int c = 0; c < NC; c++) {
        const size_t idx = ((size_t)(b * NC + c) * D_STATE + n) * D_INNER + d;
        const float p = P[idx];
        const float s = S[idx];
        P[idx] = h;
        h = fmaf(p, h, s);
    }
}

// ---------------------------------------------------------------------------
// Pass 3: local scan seeded with h_in; y = (sum h*C + D*u)*silu(z) -> bf16
// ---------------------------------------------------------------------------
__global__ __launch_bounds__(256) void scan_p3(
    const float* __restrict__ dt, const float* __restrict__ dbc,
    const __bf16* __restrict__ xc, const float* __restrict__ xz,
    const float* __restrict__ A_log, const float* __restrict__ D_skip,
    const float* __restrict__ Hin, __bf16* __restrict__ y)
{
    const int d = blockIdx.x * 256 + threadIdx.x;
    const int c = blockIdx.y;
    const int b = blockIdx.z;
    const int t0 = c * LC;

    __shared__ float Bs[LC][16], Cs[LC][16];
    #pragma unroll
    for (int r = 0; r < 2; r++) {
        const int idx = threadIdx.x + r * 256;
        const int tt = idx >> 4, n = idx & 15;
        const size_t rowoff = (size_t)(b * SEQ_L + t0 + tt) * DBC_LD + DT_RANK;
        Bs[tt][n] = dbc[rowoff + n];
        Cs[tt][n] = dbc[rowoff + D_STATE + n];
    }
    __syncthreads();

    float A[16], h[16];
    const size_t base = ((size_t)(b * NC + c) * D_STATE) * D_INNER + d;
    #pragma unroll
    for (int n = 0; n < 16; n++) {
        A[n] = -__expf(A_log[d * D_STATE + n]);
        h[n] = Hin[base + (size_t)n * D_INNER];
    }
    const float Dd = D_skip[d];

    for (int t = 0; t < LC; t++) {
        const size_t row = (size_t)(b * SEQ_L + t0 + t);
        const float dtv = dt[row * D_INNER + d];
        const float uv = (float)xc[row * D_INNER + d];
        const float dtu = dtv * uv;
        float yp = 0.f;
        #pragma unroll
        for (int n = 0; n < 16; n++) {
            const float a = __expf(dtv * A[n]);
            h[n] = fmaf(a, h[n], dtu * Bs[t][n]);
            yp = fmaf(h[n], Cs[t][n], yp);
        }
        const float zv = xz[row * (2 * D_INNER) + D_INNER + d];
        const float sig = 1.f / (1.f + __expf(-zv));
        y[row * D_INNER + d] = (__bf16)((yp + Dd * uv) * (zv * sig));
    }
}

// ---------------------------------------------------------------------------
// Final LayerNorm over D_MODEL=1024. 256 thr per token row.
// ---------------------------------------------------------------------------
__global__ __launch_bounds__(256) void layernorm_kernel(
    const float* __restrict__ x, const float* __restrict__ w,
    const float* __restrict__ bb, float* __restrict__ out)
{
    __shared__ float red[8];
    const int row = blockIdx.x;
    const float* xr = x + (size_t)row * D_MODEL;
    const int tid = threadIdx.x;

    float v[4];
    float s = 0.f;
    #pragma unroll
    for (int i = 0; i < 4; i++) { v[i] = xr[tid + i * 256]; s += v[i]; }
    #pragma unroll
    for (int off = 32; off >= 1; off >>= 1) s += __shfl_xor(s, off);
    const int wid = tid >> 6;
    if ((tid & 63) == 0) red[wid] = s;
    __syncthreads();
    const float mu = (red[0] + red[1] + red[2] + red[3]) * (1.f / D_MODEL);

    float vs = 0.f;
    #pragma unroll
    for (int i = 0; i < 4; i++) { const float dd = v[i] - mu; vs = fmaf(dd, dd, vs); }
    #pragma unroll
    for (int off = 32; off >= 1; off >>= 1) vs += __shfl_xor(vs, off);
    if ((tid & 63) == 0) red[4 + wid] = vs;
    __syncthreads();
    const float var = (red[4] + red[5] + red[6] + red[7]) * (1.f / D_MODEL);
    const float inv = rsqrtf(var + EPS_LN);

    #pragma unroll
    for (int i = 0; i < 4; i++) {
        const int c = tid + i * 256;
        out[(size_t)row * D_MODEL + c] = (v[i] - mu) * inv * w[c] + bb[c];
    }
}

// ---------------------------------------------------------------------------
extern "C" void kernel_launch(void* const* d_in, const int* in_sizes, int n_in,
                              void* d_out, int out_size, void* d_ws, size_t ws_size,
                              hipStream_t stream)
{
    const float* x_in   = (const float*)d_in[0];
    const float* W_in   = (const float*)d_in[1];
    const float* conv_w = (const float*)d_in[2];
    const float* conv_b = (const float*)d_in[3];
    const float* W_x    = (const float*)d_in[4];
    const float* W_dt   = (const float*)d_in[5];
    const float* b_dt   = (const float*)d_in[6];
    const float* A_log  = (const float*)d_in[7];
    const float* D_skip = (const float*)d_in[8];
    const float* W_out  = (const float*)d_in[9];
    const float* ln_w   = (const float*)d_in[10];
    const float* ln_b   = (const float*)d_in[11];
    float* out = (float*)d_out;

    // fp32 workspace
    float* buf_x   = (float*)d_ws;                                   // 16 MB
    float* buf_xz  = buf_x   + (size_t)NROWS * D_MODEL;              // 64 MB
    float* buf_dbc = buf_xz  + (size_t)NROWS * 2 * D_INNER;          // 2 MB
    float* buf_dt  = buf_dbc + (size_t)NROWS * DBC_LD;               // 32 MB
    float* buf_P   = buf_dt  + (size_t)NROWS * D_INNER;              // 16 MB
    float* buf_S   = buf_P   + (size_t)B_SZ * NC * D_STATE * D_INNER;// 16 MB
    // bf16 workspace
    __bf16* xbf     = (__bf16*)(buf_S + (size_t)B_SZ * NC * D_STATE * D_INNER);
    __bf16* ybf     = xbf    + (size_t)NROWS * D_MODEL;
    __bf16* xcbf    = ybf    + (size_t)NROWS * D_INNER;
    __bf16* dbcbf   = xcbf   + (size_t)NROWS * D_INNER;
    __bf16* Win_bf  = dbcbf  + (size_t)NROWS * DBC_LD;
    __bf16* Wout_bf = Win_bf + (size_t)(2 * D_INNER) * D_MODEL;
    __bf16* Wx_bf   = Wout_bf + (size_t)D_MODEL * D_INNER;
    __bf16* Wdt_bf  = Wx_bf  + (size_t)DBC_LD * D_INNER;

    const dim3 blk(256);
    const int n_el = NROWS * D_INNER;

    // one-time casts (per call)
    cast_bf16_kernel<<<(2 * D_INNER * D_MODEL) / 1024, blk, 0, stream>>>(
        W_in, Win_bf, 2 * D_INNER * D_MODEL);
    cast_bf16_kernel<<<(D_MODEL * D_INNER) / 1024, blk, 0, stream>>>(
        W_out, Wout_bf, D_MODEL * D_INNER);
    cast_bf16_kernel<<<(NROWS * D_MODEL) / 1024, blk, 0, stream>>>(
        x_in, xbf, NROWS * D_MODEL);
    pad_cast_kernel<<<(DBC_LD * D_INNER + 255) / 256, blk, 0, stream>>>(
        W_x, Wx_bf, DBC_LD, D_INNER, 97, D_INNER);          // rows 97->128
    pad_cast_kernel<<<(D_INNER * KDT + 255) / 256, blk, 0, stream>>>(
        W_dt, Wdt_bf, D_INNER, KDT, D_INNER, DT_RANK);      // cols 65->96
    hipMemcpyAsync(buf_x, x_in, (size_t)NROWS * D_MODEL * sizeof(float),
                   hipMemcpyDeviceToDevice, stream);

    for (int layer = 0; layer < N_LAYERS; layer++) {
        // xz = x @ W_in^T  (4096x4096x1024)
        gemm_mfma_nt<0><<<dim3(2 * D_INNER / 128, NROWS / 128, 1), blk, 0, stream>>>(
            xbf, Win_bf, buf_xz, nullptr, nullptr, nullptr,
            NROWS, 2 * D_INNER, D_MODEL, D_MODEL, D_MODEL, 2 * D_INNER, D_MODEL);
        // conv + silu -> xc (bf16)
        conv_silu_kernel<<<(n_el + 255) / 256, blk, 0, stream>>>(
            buf_xz, conv_w, conv_b, xcbf);
        // dbc = xc @ W_x^T  (4096x128x2048), split-K=8, atomic accumulate
        hipMemsetAsync(buf_dbc, 0, (size_t)NROWS * DBC_LD * sizeof(float), stream);
        gemm_mfma_nt<2><<<dim3(1, NROWS / 128, 8), blk, 0, stream>>>(
            xcbf, Wx_bf, buf_dbc, nullptr, nullptr, nullptr,
            NROWS, DBC_LD, D_INNER, D_INNER, D_INNER, DBC_LD, 256);
        // bf16 mirror of dbc for the dt GEMM's A operand
        cast_bf16_kernel<<<(NROWS * DBC_LD) / 1024, blk, 0, stream>>>(
            buf_dbc, dbcbf, NROWS * DBC_LD);
        // dt = softplus(dt_low @ W_dt^T + b_dt)  (4096x2048x96 padded)
        gemm_mfma_nt<3><<<dim3(D_INNER / 128, NROWS / 128, 1), blk, 0, stream>>>(
            dbcbf, Wdt_bf, buf_dt, nullptr, nullptr, b_dt,
            NROWS, D_INNER, KDT, DBC_LD, KDT, D_INNER, KDT);
        // chunk-parallel scan
        scan_p1<<<dim3(D_INNER / 256, NC, B_SZ), blk, 0, stream>>>(
            buf_dt, buf_dbc, xcbf, A_log, buf_P, buf_S);
        scan_p2<<<(B_SZ * D_STATE * D_INNER) / 256, blk, 0, stream>>>(
            buf_P, buf_S);
        scan_p3<<<dim3(D_INNER / 256, NC, B_SZ), blk, 0, stream>>>(
            buf_dt, buf_dbc, xcbf, buf_xz, A_log, D_skip, buf_P, ybf);
        // x = y @ W_out^T + x  (4096x1024x2048), fused residual + bf16 copy
        gemm_mfma_nt<1><<<dim3(D_MODEL / 128, NROWS / 128, 1), blk, 0, stream>>>(
            ybf, Wout_bf, buf_x, buf_x, xbf, nullptr,
            NROWS, D_MODEL, D_INNER, D_INNER, D_INNER, D_MODEL, D_INNER);
    }

    layernorm_kernel<<<NROWS, blk, 0, stream>>>(buf_x, ln_w, ln_b, out);
}

// Round 5
// 1082.445 us; speedup vs baseline: 7.8158x; 1.1654x over previous
//
#include <hip/hip_runtime.h>
#include <hip/hip_bf16.h>
#include <math.h>

// Problem constants
#define D_MODEL 1024
#define N_LAYERS 4
#define D_STATE 16
#define D_CONV 4
#define D_INNER 2048
#define DT_RANK 65
#define B_SZ 2
#define SEQ_L 2048
#define EPS_LN 1e-5f

#define NROWS (B_SZ * SEQ_L)          // 4096 token rows
#define DBC_LD 128                    // padded row stride for dbc (97 -> 128)
#define KDT 96                        // padded K for dt GEMM (65 -> 96)
#define NSLICE 8                      // split-K slices for dbc GEMM

// scan chunking
#define NC 64
#define LC (SEQ_L / NC)               // 32

typedef __bf16 bf16x8 __attribute__((ext_vector_type(8)));
typedef __bf16 bf16x4 __attribute__((ext_vector_type(4)));
typedef float floatx4 __attribute__((ext_vector_type(4)));

// ---------------------------------------------------------------------------
__device__ __forceinline__ void async_copy16(const void* gsrc, void* lds_dst)
{
    __builtin_amdgcn_global_load_lds(
        (const __attribute__((address_space(1))) void*)gsrc,
        (__attribute__((address_space(3))) void*)lds_dst,
        16, 0, 0);
}

// ---------------------------------------------------------------------------
// MFMA bf16 GEMM (NT): C[m,n] = sum_k A[m*lda+k]*B[n*ldb+k]
// 64x128 tile, BK=32, 256 thr = 4 waves (2x2 of 32x64), 16x16x32 MFMA.
// LDS k-segments XOR-swizzled by (row>>1)&3 -> fragment reads 2-way (free).
// Epilogues: 0 = bf16 store (Cbf)                      [GEMM1 -> xz bf16]
//            1 = += Cres, store fp32 C + bf16 Cbf      [GEMM4 residual]
//            2 = fp32 store into slice blockIdx.z      [dbc split-K]
//            3 = softplus(v + bias[n]) -> bf16 Cbf     [dt GEMM]
// ---------------------------------------------------------------------------
template <int EPI>
__global__ __launch_bounds__(256) void gemm64(
    const __bf16* __restrict__ A, const __bf16* __restrict__ B,
    float* __restrict__ C, const float* __restrict__ Cres,
    __bf16* __restrict__ Cbf, const float* __restrict__ bias,
    int M, int N, int K, int lda, int ldb, int ldc, int ksl,
    size_t slice_stride)
{
    __shared__ __bf16 As[64 * 32];    // 4 KB
    __shared__ __bf16 Bs[128 * 32];   // 8 KB

    const int tid = threadIdx.x;
    const int lane = tid & 63;
    const int w = tid >> 6;           // wave 0..3
    const int wm = w & 1;             // row half (32 rows)
    const int wn = w >> 1;            // col half (64 cols)
    const int m0 = blockIdx.y * 64;
    const int n0 = blockIdx.x * 128;

    // staging: lane covers row lrow (in 16-row group), phys k-seg (lane&3),
    // global k-seg swizzled so reads land conflict-free
    const int lrow = lane >> 2;
    const int sl = (lane & 3) ^ ((lrow >> 1) & 3);
    // fragment read: row fr in group, logical seg s=(lane>>4) -> phys offset
    const int fr = lane & 15;
    const int pk = (((lane >> 4) ^ ((fr >> 1) & 3))) * 8;

    floatx4 acc[2][4];
    #pragma unroll
    for (int i = 0; i < 2; i++)
        #pragma unroll
        for (int j = 0; j < 4; j++)
            acc[i][j] = floatx4{0.f, 0.f, 0.f, 0.f};

    const int kbeg = blockIdx.z * ksl;
    const int kend = (kbeg + ksl < K) ? (kbeg + ksl) : K;

    for (int k0 = kbeg; k0 < kend; k0 += 32) {
        // A: 4 groups of 16 rows, wave w loads group w
        const __bf16* ga = A + (size_t)(m0 + w * 16 + lrow) * lda + k0 + sl * 8;
        async_copy16(ga, &As[w * 512]);
        // B: 8 groups, wave w loads 2w, 2w+1
        #pragma unroll
        for (int g2 = 0; g2 < 2; g2++) {
            const int g = w * 2 + g2;
            const __bf16* gb = B + (size_t)(n0 + g * 16 + lrow) * ldb + k0 + sl * 8;
            async_copy16(gb, &Bs[g * 512]);
        }
        __syncthreads();

        bf16x8 af[2], bf[4];
        #pragma unroll
        for (int i = 0; i < 2; i++)
            af[i] = *(const bf16x8*)&As[(wm * 32 + i * 16 + fr) * 32 + pk];
        #pragma unroll
        for (int j = 0; j < 4; j++)
            bf[j] = *(const bf16x8*)&Bs[(wn * 64 + j * 16 + fr) * 32 + pk];

        #pragma unroll
        for (int i = 0; i < 2; i++)
            #pragma unroll
            for (int j = 0; j < 4; j++)
                acc[i][j] = __builtin_amdgcn_mfma_f32_16x16x32_bf16(
                    af[i], bf[j], acc[i][j], 0, 0, 0);

        __syncthreads();
    }

    // C/D layout: col = lane&15, row = (lane>>4)*4 + reg
    const int crow = (lane >> 4) * 4;
    const int ccol = lane & 15;
    #pragma unroll
    for (int i = 0; i < 2; i++) {
        #pragma unroll
        for (int j = 0; j < 4; j++) {
            #pragma unroll
            for (int r = 0; r < 4; r++) {
                const int gm = m0 + wm * 32 + i * 16 + crow + r;
                const int gn = n0 + wn * 64 + j * 16 + ccol;
                float v = acc[i][j][r];
                const size_t ci = (size_t)gm * ldc + gn;
                if (EPI == 0) {
                    Cbf[ci] = (__bf16)v;
                } else if (EPI == 1) {
                    v += Cres[ci];
                    C[ci] = v;
                    Cbf[ci] = (__bf16)v;
                } else if (EPI == 2) {
                    C[blockIdx.z * slice_stride + ci] = v;
                } else {  // EPI == 3
                    v += bias[gn];
                    v = fmaxf(v, 0.f) + log1pf(__expf(-fabsf(v)));
                    Cbf[ci] = (__bf16)v;
                }
            }
        }
    }
}

// ---------------------------------------------------------------------------
// reduce 8 dbc split-K slices -> fp32 dbc + bf16 mirror
// ---------------------------------------------------------------------------
__global__ __launch_bounds__(256) void reduce_dbc_kernel(
    const float* __restrict__ slices, float* __restrict__ dbc,
    __bf16* __restrict__ dbcbf)
{
    const size_t i = (size_t)blockIdx.x * 256 + threadIdx.x;
    if (i >= (size_t)NROWS * DBC_LD) return;
    float s = 0.f;
    #pragma unroll
    for (int z = 0; z < NSLICE; z++)
        s += slices[(size_t)z * NROWS * DBC_LD + i];
    dbc[i] = s;
    dbcbf[i] = (__bf16)s;
}

// ---------------------------------------------------------------------------
// fp32 -> bf16 cast, 4 elems/thread (n % 1024 == 0)
// ---------------------------------------------------------------------------
__global__ __launch_bounds__(256) void cast_bf16_kernel(
    const float* __restrict__ in, __bf16* __restrict__ out, int n)
{
    const int i = (blockIdx.x * 256 + threadIdx.x) * 4;
    if (i >= n) return;
    const float4 v = *(const float4*)(in + i);
    out[i + 0] = (__bf16)v.x;
    out[i + 1] = (__bf16)v.y;
    out[i + 2] = (__bf16)v.z;
    out[i + 3] = (__bf16)v.w;
}

// ---------------------------------------------------------------------------
// pad-cast: out[r*C_out+c] = (r<R_in && c<C_in) ? (bf16)in[r*C_in+c] : 0
// ---------------------------------------------------------------------------
__global__ __launch_bounds__(256) void pad_cast_kernel(
    const float* __restrict__ in, __bf16* __restrict__ out,
    int R_out, int C_out, int R_in, int C_in)
{
    const int i = blockIdx.x * 256 + threadIdx.x;
    if (i >= R_out * C_out) return;
    const int r = i / C_out;
    const int c = i - r * C_out;
    out[i] = (r < R_in && c < C_in) ? (__bf16)in[r * C_in + c] : (__bf16)0.f;
}

// ---------------------------------------------------------------------------
// Depthwise causal conv (D_CONV=4) + bias + SiLU. xz bf16 in, xc bf16 out.
// 4 channels per thread, vectorized loads/stores.
// ---------------------------------------------------------------------------
__global__ __launch_bounds__(256) void conv_silu_kernel(
    const __bf16* __restrict__ xz, const float* __restrict__ conv_w,
    const float* __restrict__ conv_b, __bf16* __restrict__ xc)
{
    const size_t idx4 = ((size_t)blockIdx.x * 256 + threadIdx.x) * 4;
    if (idx4 >= (size_t)NROWS * D_INNER) return;
    const int d4 = (int)(idx4 & (D_INNER - 1));
    const size_t bt = idx4 >> 11;
    const int t = (int)(bt & (SEQ_L - 1));

    float acc[4];
    const float4 cb = *(const float4*)&conv_b[d4];
    acc[0] = cb.x; acc[1] = cb.y; acc[2] = cb.z; acc[3] = cb.w;

    float4 wd[4];   // wd[q] = 4 taps of channel d4+q
    #pragma unroll
    for (int q = 0; q < 4; q++)
        wd[q] = *(const float4*)&conv_w[(d4 + q) * D_CONV];

    #pragma unroll
    for (int j = 0; j < D_CONV; j++) {
        const int tt = t + j - (D_CONV - 1);
        if (tt >= 0) {
            const size_t row = bt + j - (D_CONV - 1);
            const bf16x4 v = *(const bf16x4*)&xz[row * (2 * D_INNER) + d4];
            acc[0] = fmaf((float)v[0], ((const float*)&wd[0])[j], acc[0]);
            acc[1] = fmaf((float)v[1], ((const float*)&wd[1])[j], acc[1]);
            acc[2] = fmaf((float)v[2], ((const float*)&wd[2])[j], acc[2]);
            acc[3] = fmaf((float)v[3], ((const float*)&wd[3])[j], acc[3]);
        }
    }
    bf16x4 o;
    #pragma unroll
    for (int q = 0; q < 4; q++)
        o[q] = (__bf16)(acc[q] / (1.f + __expf(-acc[q])));
    *(bf16x4*)&xc[idx4] = o;
}

// ---------------------------------------------------------------------------
// Chunk-parallel selective scan.
// Pass 1: per (b, chunk, d) thread: P_n = prod a, S_n = local scan from 0.
// ---------------------------------------------------------------------------
__global__ __launch_bounds__(256) void scan_p1(
    const __bf16* __restrict__ dt, const float* __restrict__ dbc,
    const __bf16* __restrict__ xc, const float* __restrict__ A_log,
    float* __restrict__ P, float* __restrict__ S)
{
    const int d = blockIdx.x * 256 + threadIdx.x;
    const int c = blockIdx.y;
    const int b = blockIdx.z;
    const int t0 = c * LC;

    __shared__ float Bs[LC][16];
    #pragma unroll
    for (int r = 0; r < 2; r++) {
        const int idx = threadIdx.x + r * 256;
        const int tt = idx >> 4, n = idx & 15;
        Bs[tt][n] = dbc[(size_t)(b * SEQ_L + t0 + tt) * DBC_LD + DT_RANK + n];
    }
    __syncthreads();

    float A[16], h[16], Pr[16];
    #pragma unroll
    for (int n = 0; n < 16; n++) {
        A[n] = -__expf(A_log[d * D_STATE + n]);
        h[n] = 0.f;
        Pr[n] = 1.f;
    }

    for (int t = 0; t < LC; t++) {
        const size_t row = (size_t)(b * SEQ_L + t0 + t);
        const float dtv = (float)dt[row * D_INNER + d];
        const float uv = (float)xc[row * D_INNER + d];
        const float dtu = dtv * uv;
        #pragma unroll
        for (int n = 0; n < 16; n++) {
            const float a = __expf(dtv * A[n]);
            h[n] = fmaf(a, h[n], dtu * Bs[t][n]);
            Pr[n] *= a;
        }
    }

    const size_t base = ((size_t)(b * NC + c) * D_STATE) * D_INNER + d;
    #pragma unroll
    for (int n = 0; n < 16; n++) {
        P[base + (size_t)n * D_INNER] = Pr[n];
        S[base + (size_t)n * D_INNER] = h[n];
    }
}

// ---------------------------------------------------------------------------
// Pass 2: sequential combine over chunks; h_in written in place over P.
// ---------------------------------------------------------------------------
__global__ __launch_bounds__(256) void scan_p2(
    float* __restrict__ P, const float* __restrict__ S)
{
    const size_t g = (size_t)blockIdx.x * 256 + threadIdx.x;
    const int d = (int)(g & (D_INNER - 1));
    const int n = (int)((g >> 11) & 15);
    const int b = (int)(g >> 15);

    float h = 0.f;
    for (int c = 0; c < NC; c++) {
        const size_t idx = ((size_t)(b * NC + c) * D_STATE + n) * D_INNER + d;
        const float p = P[idx];
        const float s = S[idx];
        P[idx] = h;
        h = fmaf(p, h, s);
    }
}

// ---------------------------------------------------------------------------
// Pass 3: local scan seeded with h_in; y = (sum h*C + D*u)*silu(z) -> bf16
// ---------------------------------------------------------------------------
__global__ __launch_bounds__(256) void scan_p3(
    const __bf16* __restrict__ dt, const float* __restrict__ dbc,
    const __bf16* __restrict__ xc, const __bf16* __restrict__ xz,
    const float* __restrict__ A_log, const float* __restrict__ D_skip,
    const float* __restrict__ Hin, __bf16* __restrict__ y)
{
    const int d = blockIdx.x * 256 + threadIdx.x;
    const int c = blockIdx.y;
    const int b = blockIdx.z;
    const int t0 = c * LC;

    __shared__ float Bs[LC][16], Cs[LC][16];
    #pragma unroll
    for (int r = 0; r < 2; r++) {
        const int idx = threadIdx.x + r * 256;
        const int tt = idx >> 4, n = idx & 15;
        const size_t rowoff = (size_t)(b * SEQ_L + t0 + tt) * DBC_LD + DT_RANK;
        Bs[tt][n] = dbc[rowoff + n];
        Cs[tt][n] = dbc[rowoff + D_STATE + n];
    }
    __syncthreads();

    float A[16], h[16];
    const size_t base = ((size_t)(b * NC + c) * D_STATE) * D_INNER + d;
    #pragma unroll
    for (int n = 0; n < 16; n++) {
        A[n] = -__expf(A_log[d * D_STATE + n]);
        h[n] = Hin[base + (size_t)n * D_INNER];
    }
    const float Dd = D_skip[d];

    for (int t = 0; t < LC; t++) {
        const size_t row = (size_t)(b * SEQ_L + t0 + t);
        const float dtv = (float)dt[row * D_INNER + d];
        const float uv = (float)xc[row * D_INNER + d];
        const float dtu = dtv * uv;
        float yp = 0.f;
        #pragma unroll
        for (int n = 0; n < 16; n++) {
            const float a = __expf(dtv * A[n]);
            h[n] = fmaf(a, h[n], dtu * Bs[t][n]);
            yp = fmaf(h[n], Cs[t][n], yp);
        }
        const float zv = (float)xz[row * (2 * D_INNER) + D_INNER + d];
        const float sig = 1.f / (1.f + __expf(-zv));
        y[row * D_INNER + d] = (__bf16)((yp + Dd * uv) * (zv * sig));
    }
}

// ---------------------------------------------------------------------------
// Final LayerNorm over D_MODEL=1024. 256 thr per token row.
// ---------------------------------------------------------------------------
__global__ __launch_bounds__(256) void layernorm_kernel(
    const float* __restrict__ x, const float* __restrict__ w,
    const float* __restrict__ bb, float* __restrict__ out)
{
    __shared__ float red[8];
    const int row = blockIdx.x;
    const float* xr = x + (size_t)row * D_MODEL;
    const int tid = threadIdx.x;

    float v[4];
    float s = 0.f;
    #pragma unroll
    for (int i = 0; i < 4; i++) { v[i] = xr[tid + i * 256]; s += v[i]; }
    #pragma unroll
    for (int off = 32; off >= 1; off >>= 1) s += __shfl_xor(s, off);
    const int wid = tid >> 6;
    if ((tid & 63) == 0) red[wid] = s;
    __syncthreads();
    const float mu = (red[0] + red[1] + red[2] + red[3]) * (1.f / D_MODEL);

    float vs = 0.f;
    #pragma unroll
    for (int i = 0; i < 4; i++) { const float dd = v[i] - mu; vs = fmaf(dd, dd, vs); }
    #pragma unroll
    for (int off = 32; off >= 1; off >>= 1) vs += __shfl_xor(vs, off);
    if ((tid & 63) == 0) red[4 + wid] = vs;
    __syncthreads();
    const float var = (red[4] + red[5] + red[6] + red[7]) * (1.f / D_MODEL);
    const float inv = rsqrtf(var + EPS_LN);

    #pragma unroll
    for (int i = 0; i < 4; i++) {
        const int c = tid + i * 256;
        out[(size_t)row * D_MODEL + c] = (v[i] - mu) * inv * w[c] + bb[c];
    }
}

// ---------------------------------------------------------------------------
extern "C" void kernel_launch(void* const* d_in, const int* in_sizes, int n_in,
                              void* d_out, int out_size, void* d_ws, size_t ws_size,
                              hipStream_t stream)
{
    const float* x_in   = (const float*)d_in[0];
    const float* W_in   = (const float*)d_in[1];
    const float* conv_w = (const float*)d_in[2];
    const float* conv_b = (const float*)d_in[3];
    const float* W_x    = (const float*)d_in[4];
    const float* W_dt   = (const float*)d_in[5];
    const float* b_dt   = (const float*)d_in[6];
    const float* A_log  = (const float*)d_in[7];
    const float* D_skip = (const float*)d_in[8];
    const float* W_out  = (const float*)d_in[9];
    const float* ln_w   = (const float*)d_in[10];
    const float* ln_b   = (const float*)d_in[11];
    float* out = (float*)d_out;

    // fp32 workspace
    float* buf_x   = (float*)d_ws;                                    // 16 MB
    float* buf_dbc = buf_x   + (size_t)NROWS * D_MODEL;               // 2 MB
    float* buf_P   = buf_dbc + (size_t)NROWS * DBC_LD;                // 16 MB
    float* buf_S   = buf_P   + (size_t)B_SZ * NC * D_STATE * D_INNER; // 16 MB
    float* buf_sl  = buf_S   + (size_t)B_SZ * NC * D_STATE * D_INNER; // 16 MB
    // bf16 workspace
    __bf16* xzbf    = (__bf16*)(buf_sl + (size_t)NSLICE * NROWS * DBC_LD); // 32 MB
    __bf16* xbf     = xzbf   + (size_t)NROWS * 2 * D_INNER;           // 8 MB
    __bf16* ybf     = xbf    + (size_t)NROWS * D_MODEL;               // 16 MB
    __bf16* xcbf    = ybf    + (size_t)NROWS * D_INNER;               // 16 MB
    __bf16* dtbf    = xcbf   + (size_t)NROWS * D_INNER;               // 16 MB
    __bf16* dbcbf   = dtbf   + (size_t)NROWS * D_INNER;               // 1 MB
    __bf16* Win_bf  = dbcbf  + (size_t)NROWS * DBC_LD;
    __bf16* Wout_bf = Win_bf + (size_t)(2 * D_INNER) * D_MODEL;
    __bf16* Wx_bf   = Wout_bf + (size_t)D_MODEL * D_INNER;
    __bf16* Wdt_bf  = Wx_bf  + (size_t)DBC_LD * D_INNER;

    const dim3 blk(256);
    const int n_el = NROWS * D_INNER;

    // one-time casts (per call)
    cast_bf16_kernel<<<(2 * D_INNER * D_MODEL) / 1024, blk, 0, stream>>>(
        W_in, Win_bf, 2 * D_INNER * D_MODEL);
    cast_bf16_kernel<<<(D_MODEL * D_INNER) / 1024, blk, 0, stream>>>(
        W_out, Wout_bf, D_MODEL * D_INNER);
    cast_bf16_kernel<<<(NROWS * D_MODEL) / 1024, blk, 0, stream>>>(
        x_in, xbf, NROWS * D_MODEL);
    pad_cast_kernel<<<(DBC_LD * D_INNER + 255) / 256, blk, 0, stream>>>(
        W_x, Wx_bf, DBC_LD, D_INNER, 97, D_INNER);          // rows 97->128
    pad_cast_kernel<<<(D_INNER * KDT + 255) / 256, blk, 0, stream>>>(
        W_dt, Wdt_bf, D_INNER, KDT, D_INNER, DT_RANK);      // cols 65->96
    hipMemcpyAsync(buf_x, x_in, (size_t)NROWS * D_MODEL * sizeof(float),
                   hipMemcpyDeviceToDevice, stream);

    for (int layer = 0; layer < N_LAYERS; layer++) {
        // xz = x @ W_in^T  (4096x4096x1024) -> bf16
        gemm64<0><<<dim3(2 * D_INNER / 128, NROWS / 64, 1), blk, 0, stream>>>(
            xbf, Win_bf, nullptr, nullptr, xzbf, nullptr,
            NROWS, 2 * D_INNER, D_MODEL, D_MODEL, D_MODEL, 2 * D_INNER,
            D_MODEL, 0);
        // conv + silu -> xc (bf16)
        conv_silu_kernel<<<(n_el / 4 + 255) / 256, blk, 0, stream>>>(
            xzbf, conv_w, conv_b, xcbf);
        // dbc = xc @ W_x^T  (4096x128x2048), split-K=8 into slices
        gemm64<2><<<dim3(1, NROWS / 64, NSLICE), blk, 0, stream>>>(
            xcbf, Wx_bf, buf_sl, nullptr, nullptr, nullptr,
            NROWS, DBC_LD, D_INNER, D_INNER, D_INNER, DBC_LD,
            D_INNER / NSLICE, (size_t)NROWS * DBC_LD);
        // reduce slices -> fp32 dbc + bf16 mirror
        reduce_dbc_kernel<<<(NROWS * DBC_LD + 255) / 256, blk, 0, stream>>>(
            buf_sl, buf_dbc, dbcbf);
        // dt = softplus(dt_low @ W_dt^T + b_dt) -> bf16  (4096x2048x96)
        gemm64<3><<<dim3(D_INNER / 128, NROWS / 64, 1), blk, 0, stream>>>(
            dbcbf, Wdt_bf, nullptr, nullptr, dtbf, b_dt,
            NROWS, D_INNER, KDT, DBC_LD, KDT, D_INNER, KDT, 0);
        // chunk-parallel scan
        scan_p1<<<dim3(D_INNER / 256, NC, B_SZ), blk, 0, stream>>>(
            dtbf, buf_dbc, xcbf, A_log, buf_P, buf_S);
        scan_p2<<<(B_SZ * D_STATE * D_INNER) / 256, blk, 0, stream>>>(
            buf_P, buf_S);
        scan_p3<<<dim3(D_INNER / 256, NC, B_SZ), blk, 0, stream>>>(
            dtbf, buf_dbc, xcbf, xzbf, A_log, D_skip, buf_P, ybf);
        // x = y @ W_out^T + x  (4096x1024x2048), fused residual + bf16 copy
        gemm64<1><<<dim3(D_MODEL / 128, NROWS / 64, 1), blk, 0, stream>>>(
            ybf, Wout_bf, buf_x, buf_x, xbf, nullptr,
            NROWS, D_MODEL, D_INNER, D_INNER, D_INNER, D_MODEL, D_INNER, 0);
    }

    layernorm_kernel<<<NROWS, blk, 0, stream>>>(buf_x, ln_w, ln_b, out);
}